// Round 21
// baseline (889.593 us; speedup 1.0000x reference)
//
#include <hip/hip_runtime.h>
#include <math.h>

// Problem constants
#define NROWS 16384      // B*H*W = 16*32*32
#define NCODES 8192
#define DIMS 256
#define NCS 4            // code-slices (2048 codes each); cs = blockIdx&3
#define CEXP 288.5390082f   // 200 * log2(e): logits in exp2-space, y = CEXP*dot

// ws layout (float offsets)
#define OFF_WN   0u          // fp32 wn       8192*256
#define OFF_W2   2097152u    // fp32 w2       8192
#define OFF_ZN   2105344u    // fp32 zn       16384*256
#define OFF_WNH  6299648u    // ushort wn_hi
#define OFF_WNL  7348224u    // ushort wn_lo
#define OFF_ZNH  8396800u    // ushort zn_hi
#define OFF_ZNL  10493952u   // ushort zn_lo
#define OFF_PL1  12591104u   // [4][16384] partial top1 logit (y-space)
#define OFF_PL2  12656640u   // [4][16384] partial top2 logit
#define OFF_PS   12722176u   // [4][16384] partial sum-exp2
#define OFF_PI1  12787712u   // [4][16384] partial top1 idx (int)
#define OFF_PI2  12853248u   // [4][16384] partial top2 idx (int)
#define OFF_RM   12918784u   // 16384 final row max (y-space)
#define OFF_RS   12935168u   // 16384 final row sum-exp2
#define OFF_RIDX 12951552u   // 16384 final exact argmin (int)
#define OFF_AVGP 12967936u   // 8192 avg_probs
#define OFF_SCAL 12976128u   // [0]=cb_sum [1]=ent_sum(nat)

typedef __attribute__((ext_vector_type(8))) short bf16x8;
typedef __attribute__((ext_vector_type(4))) float f32x4;
typedef unsigned short u16;

__device__ __forceinline__ u16 f2bf(float f) {
  unsigned u = __float_as_uint(f);
  u += 0x7fffu + ((u >> 16) & 1u);
  return (u16)(u >> 16);
}
__device__ __forceinline__ float bf2f(u16 s) { return __uint_as_float(((unsigned)s) << 16); }

__device__ __forceinline__ void gl_lds16(const u16* g, u16* l) {
  __builtin_amdgcn_global_load_lds(
      (const __attribute__((address_space(1))) unsigned*)g,
      (__attribute__((address_space(3))) unsigned*)l, 16, 0, 0);
}

// Phase = 2 chunks -> 4 stage-insts/wave/phase; vmcnt(4) leaves exactly the
// next phase's stages in flight (T4).
#define PHASE_BARRIER_CNT()  asm volatile("s_waitcnt vmcnt(4) lgkmcnt(0)\n\ts_barrier" ::: "memory")
#define PHASE_BARRIER_ALL()  asm volatile("s_waitcnt vmcnt(0) lgkmcnt(0)\n\ts_barrier" ::: "memory")
#define DRAIN_VM()           asm volatile("s_waitcnt vmcnt(0)" ::: "memory")

// top-2 insert ordered by (value desc, index asc)
__device__ __forceinline__ void ins2(float x, int idx, float& b1, int& i1, float& b2, int& i2) {
  if (x > b1 || (x == b1 && idx < i1)) { b2 = b1; i2 = i1; b1 = x; i1 = idx; }
  else if (x > b2 || (x == b2 && idx < i2)) { b2 = x; i2 = idx; }
}

__global__ __launch_bounds__(256) void k0_init(float* ws) {
  int i = blockIdx.x * 256 + threadIdx.x;
  if (i < NCODES) ws[OFF_AVGP + i] = 0.f;
  if (i < 16) ws[OFF_SCAL + i] = 0.f;
}

// weight = emb @ proj_w^T + b ; wn = normalize; w2 = sum(wn^2); + bf16 hi/lo planes
__global__ __launch_bounds__(256) void k1_codebook(const float* __restrict__ emb,
    const float* __restrict__ pw, const float* __restrict__ pb,
    float* __restrict__ wn, float* __restrict__ w2,
    u16* __restrict__ wnh, u16* __restrict__ wnl) {
  __shared__ float e[256];
  __shared__ float red[256];
  int k = blockIdx.x, t = threadIdx.x;
  e[t] = emb[(size_t)k * 256 + t];
  __syncthreads();
  const float4* prow = reinterpret_cast<const float4*>(pw + (size_t)t * 256);
  float acc = pb[t];
  #pragma unroll 8
  for (int q = 0; q < 64; ++q) {
    float4 p4 = prow[q];
    acc += e[q*4+0]*p4.x + e[q*4+1]*p4.y + e[q*4+2]*p4.z + e[q*4+3]*p4.w;
  }
  red[t] = acc * acc;
  __syncthreads();
  for (int s = 128; s; s >>= 1) { if (t < s) red[t] += red[t+s]; __syncthreads(); }
  float inv = 1.f / fmaxf(sqrtf(red[0]), 1e-6f);
  float v = acc * inv;
  size_t o = (size_t)k*256 + t;
  wn[o] = v;
  u16 hb = f2bf(v); float hf = bf2f(hb);
  wnh[o] = hb; wnl[o] = f2bf(v - hf);
  __syncthreads();
  red[t] = v * v;
  __syncthreads();
  for (int s = 128; s; s >>= 1) { if (t < s) red[t] += red[t+s]; __syncthreads(); }
  if (t == 0) w2[k] = red[0];
}

// zn = normalize over channel dim; zn row-major [row][C] + bf16 hi/lo
__global__ __launch_bounds__(256) void k2_zn(const float* __restrict__ z,
    float* __restrict__ zn, u16* __restrict__ znh, u16* __restrict__ znl) {
  __shared__ float tile[256][33];
  __shared__ float inv[32];
  int bh = blockIdx.x, t = threadIdx.x;
  const float* zb = z + (size_t)(bh >> 5) * (256*1024) + (size_t)(bh & 31) * 32;
  for (int j = 0; j < 32; ++j) {
    int i = t + j*256; int c = i >> 5, w = i & 31;
    tile[c][w] = zb[(size_t)c*1024 + w];
  }
  __syncthreads();
  if (t < 32) {
    float s = 0.f;
    for (int c = 0; c < 256; ++c) { float v = tile[c][t]; s += v*v; }
    inv[t] = 1.f / fmaxf(sqrtf(s), 1e-6f);
  }
  __syncthreads();
  size_t base = (size_t)bh * 32 * 256;
  for (int w = 0; w < 32; ++w) {
    float v = tile[t][w] * inv[w];
    size_t o = base + (size_t)w*256 + t;
    zn[o] = v;
    u16 hb = f2bf(v); float hf = bf2f(hb);
    znh[o] = hb; znl[o] = f2bf(v - hf);
  }
}

// ---- Pass 1 (MFMA): per-row online (max, sum-exp2, per-lane top-2). ----
// R20 closure: VALUBusy 26% is 6x the source-level stats count; WRITE_SIZE
// 27MB/dispatch is scratch; VGPR pinned at 128 vs ~220 live. The allocator's
// 128-VGPR ceiling (ignored waves_per_eu AND the R18 pin -> spill) puts
// spill/reload on every phase's critical path, serializing the three ~27%
// pipes. FINAL test: make the working set FIT 128 VGPRs. 16 rows/wave
// (jr dim dropped): bh/bl=64 + acc=32 + misc ~= 116 < 128, zero spill.
// Cost: grid 512 (128 rows/block), 2x LDS-read + staged totals. If de-spill
// restores pipe overlap -> ~180-230us/pass; if invariant AGAIN -> structure
// is at its HIP-source ceiling.
__global__ __attribute__((amdgpu_flat_work_group_size(512,512)))
__attribute__((amdgpu_waves_per_eu(2,2))) void k3_pass1(
    const u16* __restrict__ znh, const u16* __restrict__ znl,
    const u16* __restrict__ wnh, const u16* __restrict__ wnl,
    float* __restrict__ pL1, float* __restrict__ pL2, float* __restrict__ pS,
    int* __restrict__ pI1, int* __restrict__ pI2) {
  __shared__ u16 Cbuf[6][2][128*32];    // 96 KiB ring of chunk-slots
  int t = threadIdx.x;
  int rb = blockIdx.x >> 2, cs = blockIdx.x & 3;
  int r0 = rb * 128;
  int w = t >> 6, l = t & 63;
  int g = l >> 4, lr = l & 15;
  int slotA = ((lr >> 1) & 3);          // read-side XOR component

  // 16 rows per wave: B-fragments fit registers with NO spill
  bf16x8 bh[8], bl[8];
  {
    size_t rbase = (size_t)(r0 + w*16 + lr) * 256;
    #pragma unroll
    for (int dc = 0; dc < 8; ++dc) {
      bh[dc] = *(const bf16x8*)&znh[rbase + dc*32 + g*8];
      bl[dc] = *(const bf16x8*)&znl[rbase + dc*32 + g*8];
    }
  }

  const size_t csbase = (size_t)cs * 2048 * 256;
  auto stage = [&](int s, int b) {       // 2 VMEM insts per wave, coalesced
    int dc2 = s & 7;
    int krow = (s >> 3) * 128;
    int c = w*16 + (l >> 2);
    int qs = (l & 3) ^ ((l >> 3) & 3);   // inverse-swizzled source quad (same 64B line)
    size_t go = csbase + (size_t)(krow + c)*256 + dc2*32 + qs*8;
    gl_lds16(&wnh[go], &Cbuf[b][0][w*512]);
    gl_lds16(&wnl[go], &Cbuf[b][1][w*512]);
  };
  DRAIN_VM();
  stage(0, 0);
  stage(1, 1);
  stage(2, 2);
  stage(3, 3);

  float b1 = -3.0e38f, b2 = -3.0e38f, Sv = 0.f;
  int i1 = 0, i2 = 0;                   // encoded kt*32+n

  for (int kt = 0; kt < 16; ++kt) {
    f32x4 acc[8];
    #pragma unroll
    for (int i = 0; i < 8; ++i) acc[i] = (f32x4){0.f,0.f,0.f,0.f};
    #pragma unroll
    for (int dcp = 0; dcp < 4; ++dcp) {          // phase = 2 chunks (BK=64)
      int s0 = kt*8 + dcp*2;
      if (s0 < 126) PHASE_BARRIER_CNT(); else PHASE_BARRIER_ALL();
      if (s0 + 4 < 128) { int b4 = (s0+4) % 6; stage(s0 + 4, b4); }
      if (s0 + 5 < 128) { int b5 = (s0+5) % 6; stage(s0 + 5, b5); }
      #pragma unroll
      for (int h = 0; h < 2; ++h) {
        int dc = dcp*2 + h;
        int bR = (s0 + h) % 6;
        #pragma unroll
        for (int i = 0; i < 8; ++i) {
          int co = (i*16 + lr)*32 + (g ^ slotA)*8;    // swizzled read: conflict-free
          bf16x8 ah = *(const bf16x8*)&Cbuf[bR][0][co];
          bf16x8 al = *(const bf16x8*)&Cbuf[bR][1][co];
          acc[i] = __builtin_amdgcn_mfma_f32_16x16x32_bf16(ah, bh[dc], acc[i], 0, 0, 0);
          acc[i] = __builtin_amdgcn_mfma_f32_16x16x32_bf16(ah, bl[dc], acc[i], 0, 0, 0);
          acc[i] = __builtin_amdgcn_mfma_f32_16x16x32_bf16(al, bh[dc], acc[i], 0, 0, 0);
        }
      }
    }
    // per-kt stats: raw-acc top-2 chain + exp2-space sumexp (lane-local)
    int kb32 = kt * 32;
    {
      float ob1 = b1;
      #pragma unroll
      for (int n = 0; n < 32; ++n) {
        float x = acc[n>>2][n&3];
        bool c1 = x > b1;
        bool c2 = x > b2;
        float hi = fmaxf(x, b1);
        float lo = fminf(x, b1);
        b2 = fmaxf(lo, fminf(hi, b2));
        i2 = c1 ? i1 : (c2 ? (kb32 + n) : i2);
        b1 = hi;
        i1 = c1 ? (kb32 + n) : i1;
      }
      float negCm = -CEXP * b1;
      float ts0 = 0.f, ts1 = 0.f;
      #pragma unroll
      for (int n = 0; n < 32; n += 2) {
        ts0 += exp2f(fmaf(CEXP, acc[n>>2][n&3],         negCm));
        ts1 += exp2f(fmaf(CEXP, acc[(n+1)>>2][(n+1)&3], negCm));
      }
      Sv = Sv * exp2f(CEXP * (ob1 - b1)) + (ts0 + ts1);
    }
  }
  // decode indices, convert to y-space, merge lanes over g (masks 16,32)
  float my, y2; int gi1, gi2;
  {
    int base = cs*2048 + g*4;
    gi1 = base + (i1>>5)*128 + ((i1>>2)&7)*16 + (i1&3);
    gi2 = base + (i2>>5)*128 + ((i2>>2)&7)*16 + (i2&3);
    my = CEXP * b1;
    y2 = CEXP * b2;
    #pragma unroll
    for (int mask = 16; mask <= 32; mask <<= 1) {
      float om  = __shfl_xor(my, mask, 64);
      float oy2 = __shfl_xor(y2, mask, 64);
      float oS  = __shfl_xor(Sv, mask, 64);
      int   o1  = __shfl_xor(gi1, mask, 64);
      int   o2  = __shfl_xor(gi2, mask, 64);
      float pm = my;
      ins2(om,  o1, my, gi1, y2, gi2);
      ins2(oy2, o2, my, gi1, y2, gi2);
      Sv = Sv * exp2f(pm - my) + oS * exp2f(om - my);
    }
  }
  if (g == 0) {
    int r = r0 + w*16 + lr;
    size_t o = (size_t)cs * NROWS + r;
    pL1[o] = my; pL2[o] = y2; pS[o] = Sv;
    pI1[o] = gi1; pI2[o] = gi2;
  }
}

// merge 4 code-slice partials; exact fp32 re-score of top-2 -> final argmin
__global__ __launch_bounds__(256) void k3b_refine(
    const float* __restrict__ zn, const float* __restrict__ wn, const float* __restrict__ w2,
    const float* __restrict__ pL1, const float* __restrict__ pL2, const float* __restrict__ pS,
    const int* __restrict__ pI1, const int* __restrict__ pI2,
    float* __restrict__ rm, float* __restrict__ rs, int* __restrict__ ridx) {
  int t = threadIdx.x;
  int r = blockIdx.x * 4 + (t >> 6);
  int l = t & 63;
  float b1 = pL1[r], b2 = pL2[r], S = pS[r];
  int i1 = pI1[r], i2 = pI2[r];
  #pragma unroll
  for (int c = 1; c < NCS; ++c) {
    size_t o = (size_t)c * NROWS + r;
    float ob1 = pL1[o], ob2 = pL2[o], oS = pS[o];
    int oi1 = pI1[o], oi2 = pI2[o];
    float pb1 = b1;
    ins2(ob1, oi1, b1, i1, b2, i2);
    ins2(ob2, oi2, b1, i1, b2, i2);
    S = S * exp2f(pb1 - b1) + oS * exp2f(ob1 - b1);
  }
  int cand = (l < 32) ? i1 : i2;
  int lo = l & 31;
  const float* zr = zn + (size_t)r * 256;
  const float* wc = wn + (size_t)cand * 256;
  float d = 0.f;
  #pragma unroll
  for (int q = 0; q < 8; ++q) d += zr[lo + q*32] * wc[lo + q*32];
  #pragma unroll
  for (int mask = 1; mask <= 16; mask <<= 1) d += __shfl_xor(d, mask, 64);
  float dOther = __shfl_xor(d, 32, 64);
  if (l == 0) {
    float s1 = w2[i1] - 2.f*d;       // exact, z2 common term dropped
    float s2 = w2[i2] - 2.f*dOther;
    int win = i1;
    if (s2 < s1 || (s2 == s1 && i2 < i1)) win = i2;
    rm[r] = b1; rs[r] = S; ridx[r] = win;
  }
}

// ---- Pass 2 (MFMA): recompute logits; avg_probs + sample entropy ----
__global__ __attribute__((amdgpu_flat_work_group_size(512,512)))
__attribute__((amdgpu_waves_per_eu(2,2))) void k4_pass2(
    const u16* __restrict__ znh, const u16* __restrict__ znl,
    const u16* __restrict__ wnh, const u16* __restrict__ wnl,
    const float* __restrict__ rm, const float* __restrict__ rs,
    float* __restrict__ avgp, float* __restrict__ scal) {
  __shared__ u16 Cbuf[6][2][128*32];   // 96 KiB ring
  __shared__ float avgSlice[2048];     // 8 KiB: full cs slice accumulator
  __shared__ float red[512];
  int t = threadIdx.x;
  int rb = blockIdx.x >> 2, cs = blockIdx.x & 3;
  int r0 = rb * 128;
  int w = t >> 6, l = t & 63;
  int g = l >> 4, lr = l & 15;
  int slotA = ((lr >> 1) & 3);

  for (int i = t; i < 2048; i += 512) avgSlice[i] = 0.f;

  bf16x8 bh[8], bl[8];
  {
    size_t rbase = (size_t)(r0 + w*16 + lr) * 256;
    #pragma unroll
    for (int dc = 0; dc < 8; ++dc) {
      bh[dc] = *(const bf16x8*)&znh[rbase + dc*32 + g*8];
      bl[dc] = *(const bf16x8*)&znl[rbase + dc*32 + g*8];
    }
  }
  float m_, invS, l2s;
  {
    int r = r0 + w*16 + lr;
    float mm = rm[r], ss = rs[r];
    m_ = mm; invS = 1.f / ss; l2s = log2f(ss);
  }

  const size_t csbase = (size_t)cs * 2048 * 256;
  auto stage = [&](int s, int b) {
    int dc2 = s & 7;
    int krow = (s >> 3) * 128;
    int c = w*16 + (l >> 2);
    int qs = (l & 3) ^ ((l >> 3) & 3);
    size_t go = csbase + (size_t)(krow + c)*256 + dc2*32 + qs*8;
    gl_lds16(&wnh[go], &Cbuf[b][0][w*512]);
    gl_lds16(&wnl[go], &Cbuf[b][1][w*512]);
  };
  DRAIN_VM();
  stage(0, 0);
  stage(1, 1);
  stage(2, 2);
  stage(3, 3);
  float ent = 0.f;

  for (int kt = 0; kt < 16; ++kt) {
    f32x4 acc[8];
    #pragma unroll
    for (int i = 0; i < 8; ++i) acc[i] = (f32x4){0.f,0.f,0.f,0.f};
    #pragma unroll
    for (int dcp = 0; dcp < 4; ++dcp) {
      int s0 = kt*8 + dcp*2;
      if (s0 < 126) PHASE_BARRIER_CNT(); else PHASE_BARRIER_ALL();
      if (s0 + 4 < 128) { int b4 = (s0+4) % 6; stage(s0 + 4, b4); }
      if (s0 + 5 < 128) { int b5 = (s0+5) % 6; stage(s0 + 5, b5); }
      #pragma unroll
      for (int h = 0; h < 2; ++h) {
        int dc = dcp*2 + h;
        int bR = (s0 + h) % 6;
        #pragma unroll
        for (int i = 0; i < 8; ++i) {
          int co = (i*16 + lr)*32 + (g ^ slotA)*8;
          bf16x8 ah = *(const bf16x8*)&Cbuf[bR][0][co];
          bf16x8 al = *(const bf16x8*)&Cbuf[bR][1][co];
          acc[i] = __builtin_amdgcn_mfma_f32_16x16x32_bf16(ah, bh[dc], acc[i], 0, 0, 0);
          acc[i] = __builtin_amdgcn_mfma_f32_16x16x32_bf16(ah, bl[dc], acc[i], 0, 0, 0);
          acc[i] = __builtin_amdgcn_mfma_f32_16x16x32_bf16(al, bh[dc], acc[i], 0, 0, 0);
        }
      }
    }
    int kb = cs*2048 + kt*128;
    // stats in two halves of 16 codeAcc (limits live registers)
    #pragma unroll
    for (int half = 0; half < 2; ++half) {
      float ca[16];
      #pragma unroll
      for (int n = 0; n < 16; ++n) ca[n] = 0.f;
      #pragma unroll
      for (int ii = 0; ii < 4; ++ii) {
        int i = half*4 + ii;
        #pragma unroll
        for (int v = 0; v < 4; ++v) {
          float tt = fmaf(CEXP, acc[i][v], -m_);
          float p = exp2f(tt) * invS;
          ent -= p * (tt - l2s);
          ca[ii*4+v] += p;
        }
      }
      #pragma unroll
      for (int n = 0; n < 16; ++n) {
        float sv = ca[n];
        sv += __shfl_xor(sv, 1, 64);
        sv += __shfl_xor(sv, 2, 64);
        sv += __shfl_xor(sv, 4, 64);
        sv += __shfl_xor(sv, 8, 64);
        if (lr == 0)
          atomicAdd(&avgSlice[kt*128 + (half*4 + (n>>2))*16 + g*4 + (n&3)], sv);
      }
    }
  }
  __syncthreads();
  for (int i = t; i < 2048; i += 512)
    atomicAdd(&avgp[cs*2048 + i], avgSlice[i] * (1.f/16384.f));
  red[t] = ent;
  __syncthreads();
  for (int s2 = 256; s2; s2 >>= 1) { if (t < s2) red[t] += red[t + s2]; __syncthreads(); }
  if (t == 0) atomicAdd(&scal[1], red[0] * 0.6931471806f);   // exp2-space -> nat
}

// gather q = wn[idx], codebook loss, write z_q channel-first
__global__ __launch_bounds__(256) void k5_gather(const float* __restrict__ zn,
    const float* __restrict__ wn, const int* __restrict__ row_idx,
    float* __restrict__ out_zq, float* __restrict__ scal) {
  __shared__ float tile[256][33];
  __shared__ float red4[4];
  __shared__ float red[256];
  int bh = blockIdx.x, t = threadIdx.x;
  int b = bh >> 5, h = bh & 31;
  float cb = 0.f;
  for (int w = 0; w < 32; ++w) {
    int r = bh*32 + w;
    int idx = row_idx[r];
    float q = wn[(size_t)idx*256 + t];
    float s = q*q;
    #pragma unroll
    for (int mask = 32; mask; mask >>= 1) s += __shfl_xor(s, mask, 64);
    if ((t & 63) == 0) red4[t >> 6] = s;
    __syncthreads();
    float tot = red4[0] + red4[1] + red4[2] + red4[3];
    float inv = 1.f / fmaxf(sqrtf(tot), 1e-6f);
    float zv = zn[(size_t)r*256 + t];
    float d = q*inv - zv;
    cb += d*d;
    tile[t][w] = q;
    __syncthreads();
  }
  red[t] = cb;
  __syncthreads();
  for (int s2 = 128; s2; s2 >>= 1) { if (t < s2) red[t] += red[t+s2]; __syncthreads(); }
  if (t == 0) atomicAdd(&scal[0], red[0]);
  float* ob = out_zq + (size_t)b*256*1024 + (size_t)h*32;
  for (int j = 0; j < 32; ++j) {
    int i = t + j*256; int c = i >> 5, ww = i & 31;
    ob[(size_t)c*1024 + ww] = tile[c][ww];
  }
}

// finalize scalars + emit indices as float
__global__ __launch_bounds__(256) void k6_final(const float* __restrict__ avg_probs,
    const float* __restrict__ scal, const int* __restrict__ row_idx,
    float* __restrict__ out) {
  int t = threadIdx.x;
  if (blockIdx.x < 64) {
    int r = blockIdx.x*256 + t;
    out[4194307 + r] = (float)row_idx[r];
    return;
  }
  __shared__ float red[256];
  float s = 0.f;
  for (int j = 0; j < 32; ++j) {
    float v = avg_probs[t + j*256];
    s -= v * logf(v + 1e-5f);
  }
  red[t] = s;
  __syncthreads();
  for (int q = 128; q; q >>= 1) { if (t < q) red[t] += red[t+q]; __syncthreads(); }
  if (t == 0) {
    float avg_entropy = red[0];
    float sample_entropy = scal[1] * (1.f/16384.f);
    float cb = scal[0] * (1.f/4194304.f);
    out[4194304] = cb;
    out[4194305] = 0.25f * cb;
    out[4194306] = 0.1f * (sample_entropy - avg_entropy);
  }
}

extern "C" void kernel_launch(void* const* d_in, const int* in_sizes, int n_in,
                              void* d_out, int out_size, void* d_ws, size_t ws_size,
                              hipStream_t stream) {
  const float* z   = (const float*)d_in[0];
  const float* emb = (const float*)d_in[1];
  const float* pw  = (const float*)d_in[2];
  const float* pb  = (const float*)d_in[3];
  float* ws  = (float*)d_ws;
  float* out = (float*)d_out;
  float* wn   = ws + OFF_WN;
  float* w2   = ws + OFF_W2;
  float* zn   = ws + OFF_ZN;
  u16*   wnh  = (u16*)(ws + OFF_WNH);
  u16*   wnl  = (u16*)(ws + OFF_WNL);
  u16*   znh  = (u16*)(ws + OFF_ZNH);
  u16*   znl  = (u16*)(ws + OFF_ZNL);
  float* pL1  = ws + OFF_PL1;
  float* pL2  = ws + OFF_PL2;
  float* pS   = ws + OFF_PS;
  int*   pI1  = (int*)(ws + OFF_PI1);
  int*   pI2  = (int*)(ws + OFF_PI2);
  float* rm   = ws + OFF_RM;
  float* rs   = ws + OFF_RS;
  int*   ridx = (int*)(ws + OFF_RIDX);
  float* avgp = ws + OFF_AVGP;
  float* scal = ws + OFF_SCAL;

  k0_init<<<32, 256, 0, stream>>>(ws);
  k1_codebook<<<NCODES, 256, 0, stream>>>(emb, pw, pb, wn, w2, wnh, wnl);
  k2_zn<<<512, 256, 0, stream>>>(z, zn, znh, znl);
  k3_pass1<<<512, 512, 0, stream>>>(znh, znl, wnh, wnl, pL1, pL2, pS, pI1, pI2);
  k3b_refine<<<NROWS/4, 256, 0, stream>>>(zn, wn, w2, pL1, pL2, pS, pI1, pI2, rm, rs, ridx);
  k4_pass2<<<512, 512, 0, stream>>>(znh, znl, wnh, wnl, rm, rs, avgp, scal);
  k5_gather<<<512, 256, 0, stream>>>(zn, wn, ridx, out, scal);
  k6_final<<<65, 256, 0, stream>>>(avgp, scal, ridx, out);
}

// Round 22
// 801.004 us; speedup vs baseline: 1.1106x; 1.1106x over previous
//
#include <hip/hip_runtime.h>
#include <math.h>

// Problem constants
#define NROWS 16384      // B*H*W = 16*32*32
#define NCODES 8192
#define DIMS 256
#define NCS 4            // code-slices (2048 codes each); cs = blockIdx&3
#define CEXP 288.5390082f   // 200 * log2(e): logits in exp2-space, y = CEXP*dot

// ws layout (float offsets)
#define OFF_WN   0u          // fp32 wn       8192*256
#define OFF_W2   2097152u    // fp32 w2       8192
#define OFF_ZN   2105344u    // fp32 zn       16384*256
#define OFF_WNH  6299648u    // ushort wn_hi
#define OFF_WNL  7348224u    // ushort wn_lo
#define OFF_ZNH  8396800u    // ushort zn_hi
#define OFF_ZNL  10493952u   // ushort zn_lo
#define OFF_PL1  12591104u   // [4][16384] partial top1 logit (y-space)
#define OFF_PL2  12656640u   // [4][16384] partial top2 logit
#define OFF_PS   12722176u   // [4][16384] partial sum-exp2
#define OFF_PI1  12787712u   // [4][16384] partial top1 idx (int)
#define OFF_PI2  12853248u   // [4][16384] partial top2 idx (int)
#define OFF_RM   12918784u   // 16384 final row max (y-space)
#define OFF_RS   12935168u   // 16384 final row sum-exp2
#define OFF_RIDX 12951552u   // 16384 final exact argmin (int)
#define OFF_AVGP 12967936u   // 8192 avg_probs
#define OFF_SCAL 12976128u   // [0]=cb_sum [1]=ent_sum(nat)

typedef __attribute__((ext_vector_type(8))) short bf16x8;
typedef __attribute__((ext_vector_type(4))) float f32x4;
typedef unsigned short u16;

__device__ __forceinline__ u16 f2bf(float f) {
  unsigned u = __float_as_uint(f);
  u += 0x7fffu + ((u >> 16) & 1u);
  return (u16)(u >> 16);
}
__device__ __forceinline__ float bf2f(u16 s) { return __uint_as_float(((unsigned)s) << 16); }

__device__ __forceinline__ void gl_lds16(const u16* g, u16* l) {
  __builtin_amdgcn_global_load_lds(
      (const __attribute__((address_space(1))) unsigned*)g,
      (__attribute__((address_space(3))) unsigned*)l, 16, 0, 0);
}

// Phase = 2 chunks -> 4 stage-insts per STAGING wave per phase; vmcnt(4)
// leaves exactly the next phase's stages in flight (T4). Non-staging waves
// have 0 outstanding VMEM -> the wait is a no-op for them.
#define PHASE_BARRIER_CNT()  asm volatile("s_waitcnt vmcnt(4) lgkmcnt(0)\n\ts_barrier" ::: "memory")
#define PHASE_BARRIER_ALL()  asm volatile("s_waitcnt vmcnt(0) lgkmcnt(0)\n\ts_barrier" ::: "memory")
#define DRAIN_VM()           asm volatile("s_waitcnt vmcnt(0)" ::: "memory")

// top-2 insert ordered by (value desc, index asc)
__device__ __forceinline__ void ins2(float x, int idx, float& b1, int& i1, float& b2, int& i2) {
  if (x > b1 || (x == b1 && idx < i1)) { b2 = b1; i2 = i1; b1 = x; i1 = idx; }
  else if (x > b2 || (x == b2 && idx < i2)) { b2 = x; i2 = idx; }
}

__global__ __launch_bounds__(256) void k0_init(float* ws) {
  int i = blockIdx.x * 256 + threadIdx.x;
  if (i < NCODES) ws[OFF_AVGP + i] = 0.f;
  if (i < 16) ws[OFF_SCAL + i] = 0.f;
}

// weight = emb @ proj_w^T + b ; wn = normalize; w2 = sum(wn^2); + bf16 hi/lo planes
__global__ __launch_bounds__(256) void k1_codebook(const float* __restrict__ emb,
    const float* __restrict__ pw, const float* __restrict__ pb,
    float* __restrict__ wn, float* __restrict__ w2,
    u16* __restrict__ wnh, u16* __restrict__ wnl) {
  __shared__ float e[256];
  __shared__ float red[256];
  int k = blockIdx.x, t = threadIdx.x;
  e[t] = emb[(size_t)k * 256 + t];
  __syncthreads();
  const float4* prow = reinterpret_cast<const float4*>(pw + (size_t)t * 256);
  float acc = pb[t];
  #pragma unroll 8
  for (int q = 0; q < 64; ++q) {
    float4 p4 = prow[q];
    acc += e[q*4+0]*p4.x + e[q*4+1]*p4.y + e[q*4+2]*p4.z + e[q*4+3]*p4.w;
  }
  red[t] = acc * acc;
  __syncthreads();
  for (int s = 128; s; s >>= 1) { if (t < s) red[t] += red[t+s]; __syncthreads(); }
  float inv = 1.f / fmaxf(sqrtf(red[0]), 1e-6f);
  float v = acc * inv;
  size_t o = (size_t)k*256 + t;
  wn[o] = v;
  u16 hb = f2bf(v); float hf = bf2f(hb);
  wnh[o] = hb; wnl[o] = f2bf(v - hf);
  __syncthreads();
  red[t] = v * v;
  __syncthreads();
  for (int s = 128; s; s >>= 1) { if (t < s) red[t] += red[t+s]; __syncthreads(); }
  if (t == 0) w2[k] = red[0];
}

// zn = normalize over channel dim; zn row-major [row][C] + bf16 hi/lo
__global__ __launch_bounds__(256) void k2_zn(const float* __restrict__ z,
    float* __restrict__ zn, u16* __restrict__ znh, u16* __restrict__ znl) {
  __shared__ float tile[256][33];
  __shared__ float inv[32];
  int bh = blockIdx.x, t = threadIdx.x;
  const float* zb = z + (size_t)(bh >> 5) * (256*1024) + (size_t)(bh & 31) * 32;
  for (int j = 0; j < 32; ++j) {
    int i = t + j*256; int c = i >> 5, w = i & 31;
    tile[c][w] = zb[(size_t)c*1024 + w];
  }
  __syncthreads();
  if (t < 32) {
    float s = 0.f;
    for (int c = 0; c < 256; ++c) { float v = tile[c][t]; s += v*v; }
    inv[t] = 1.f / fmaxf(sqrtf(s), 1e-6f);
  }
  __syncthreads();
  size_t base = (size_t)bh * 32 * 256;
  for (int w = 0; w < 32; ++w) {
    float v = tile[t][w] * inv[w];
    size_t o = base + (size_t)w*256 + t;
    zn[o] = v;
    u16 hb = f2bf(v); float hf = bf2f(hb);
    znh[o] = hb; znl[o] = f2bf(v - hf);
  }
}

// ---- Pass 1 (MFMA): per-row online (max, sum-exp2, per-lane top-2). ----
// R21 closure: de-spill alone regressed (2x work). The never-tested lever:
// waves/SIMD. Occupancy read ~8 waves/CU (2/SIMD) in EVERY round; R13's
// 512-thr test didn't challenge the ~2-workgroup pin since 1x8 == 2x4 waves.
// A 1024-THREAD WORKGROUP forces 16 co-resident waves (4/SIMD) by
// definition -- no scheduler heuristic can refuse. With all pipes at ~27%
// and no overlap, 4 waves/SIMD lets wave A's MFMA overlap wave B's LDS/VALU
// (m114). 16 waves x 16 rows = 256 rows/block, grid 256: same total work and
// staged traffic as the 782us best; LDS reads 2x (absorbed at ~50% pipe).
// Waves 0-7 stage exactly as before; waves 8-15 compute only.
__global__ __attribute__((amdgpu_flat_work_group_size(1024,1024)))
__attribute__((amdgpu_waves_per_eu(4,4))) void k3_pass1(
    const u16* __restrict__ znh, const u16* __restrict__ znl,
    const u16* __restrict__ wnh, const u16* __restrict__ wnl,
    float* __restrict__ pL1, float* __restrict__ pL2, float* __restrict__ pS,
    int* __restrict__ pI1, int* __restrict__ pI2) {
  __shared__ u16 Cbuf[6][2][128*32];    // 96 KiB ring of chunk-slots
  int t = threadIdx.x;
  int rb = blockIdx.x >> 2, cs = blockIdx.x & 3;
  int r0 = rb * 256;
  int w = t >> 6, l = t & 63;
  int g = l >> 4, lr = l & 15;
  int slotA = ((lr >> 1) & 3);          // read-side XOR component

  // 16 rows per wave: B-fragments fit 128 VGPRs with NO spill (R21-verified)
  bf16x8 bh[8], bl[8];
  {
    size_t rbase = (size_t)(r0 + w*16 + lr) * 256;
    #pragma unroll
    for (int dc = 0; dc < 8; ++dc) {
      bh[dc] = *(const bf16x8*)&znh[rbase + dc*32 + g*8];
      bl[dc] = *(const bf16x8*)&znl[rbase + dc*32 + g*8];
    }
  }

  const size_t csbase = (size_t)cs * 2048 * 256;
  auto stage = [&](int s, int b) {       // waves 0-7: 2 VMEM insts, coalesced
    if (w < 8) {
      int dc2 = s & 7;
      int krow = (s >> 3) * 128;
      int c = w*16 + (l >> 2);
      int qs = (l & 3) ^ ((l >> 3) & 3); // inverse-swizzled source quad (same 64B line)
      size_t go = csbase + (size_t)(krow + c)*256 + dc2*32 + qs*8;
      gl_lds16(&wnh[go], &Cbuf[b][0][w*512]);
      gl_lds16(&wnl[go], &Cbuf[b][1][w*512]);
    }
  };
  DRAIN_VM();
  stage(0, 0);
  stage(1, 1);
  stage(2, 2);
  stage(3, 3);

  float b1 = -3.0e38f, b2 = -3.0e38f, Sv = 0.f;
  int i1 = 0, i2 = 0;                   // encoded kt*32+n

  for (int kt = 0; kt < 16; ++kt) {
    f32x4 acc[8];
    #pragma unroll
    for (int i = 0; i < 8; ++i) acc[i] = (f32x4){0.f,0.f,0.f,0.f};
    #pragma unroll
    for (int dcp = 0; dcp < 4; ++dcp) {          // phase = 2 chunks (BK=64)
      int s0 = kt*8 + dcp*2;
      if (s0 < 126) PHASE_BARRIER_CNT(); else PHASE_BARRIER_ALL();
      if (s0 + 4 < 128) { int b4 = (s0+4) % 6; stage(s0 + 4, b4); }
      if (s0 + 5 < 128) { int b5 = (s0+5) % 6; stage(s0 + 5, b5); }
      #pragma unroll
      for (int h = 0; h < 2; ++h) {
        int dc = dcp*2 + h;
        int bR = (s0 + h) % 6;
        #pragma unroll
        for (int i = 0; i < 8; ++i) {
          int co = (i*16 + lr)*32 + (g ^ slotA)*8;    // swizzled read: conflict-free
          bf16x8 ah = *(const bf16x8*)&Cbuf[bR][0][co];
          bf16x8 al = *(const bf16x8*)&Cbuf[bR][1][co];
          acc[i] = __builtin_amdgcn_mfma_f32_16x16x32_bf16(ah, bh[dc], acc[i], 0, 0, 0);
          acc[i] = __builtin_amdgcn_mfma_f32_16x16x32_bf16(ah, bl[dc], acc[i], 0, 0, 0);
          acc[i] = __builtin_amdgcn_mfma_f32_16x16x32_bf16(al, bh[dc], acc[i], 0, 0, 0);
        }
      }
    }
    // per-kt stats: raw-acc top-2 chain + exp2-space sumexp (lane-local)
    int kb32 = kt * 32;
    {
      float ob1 = b1;
      #pragma unroll
      for (int n = 0; n < 32; ++n) {
        float x = acc[n>>2][n&3];
        bool c1 = x > b1;
        bool c2 = x > b2;
        float hi = fmaxf(x, b1);
        float lo = fminf(x, b1);
        b2 = fmaxf(lo, fminf(hi, b2));
        i2 = c1 ? i1 : (c2 ? (kb32 + n) : i2);
        b1 = hi;
        i1 = c1 ? (kb32 + n) : i1;
      }
      float negCm = -CEXP * b1;
      float ts0 = 0.f, ts1 = 0.f;
      #pragma unroll
      for (int n = 0; n < 32; n += 2) {
        ts0 += exp2f(fmaf(CEXP, acc[n>>2][n&3],         negCm));
        ts1 += exp2f(fmaf(CEXP, acc[(n+1)>>2][(n+1)&3], negCm));
      }
      Sv = Sv * exp2f(CEXP * (ob1 - b1)) + (ts0 + ts1);
    }
  }
  // decode indices, convert to y-space, merge lanes over g (masks 16,32)
  float my, y2; int gi1, gi2;
  {
    int base = cs*2048 + g*4;
    gi1 = base + (i1>>5)*128 + ((i1>>2)&7)*16 + (i1&3);
    gi2 = base + (i2>>5)*128 + ((i2>>2)&7)*16 + (i2&3);
    my = CEXP * b1;
    y2 = CEXP * b2;
    #pragma unroll
    for (int mask = 16; mask <= 32; mask <<= 1) {
      float om  = __shfl_xor(my, mask, 64);
      float oy2 = __shfl_xor(y2, mask, 64);
      float oS  = __shfl_xor(Sv, mask, 64);
      int   o1  = __shfl_xor(gi1, mask, 64);
      int   o2  = __shfl_xor(gi2, mask, 64);
      float pm = my;
      ins2(om,  o1, my, gi1, y2, gi2);
      ins2(oy2, o2, my, gi1, y2, gi2);
      Sv = Sv * exp2f(pm - my) + oS * exp2f(om - my);
    }
  }
  if (g == 0) {
    int r = r0 + w*16 + lr;
    size_t o = (size_t)cs * NROWS + r;
    pL1[o] = my; pL2[o] = y2; pS[o] = Sv;
    pI1[o] = gi1; pI2[o] = gi2;
  }
}

// merge 4 code-slice partials; exact fp32 re-score of top-2 -> final argmin
__global__ __launch_bounds__(256) void k3b_refine(
    const float* __restrict__ zn, const float* __restrict__ wn, const float* __restrict__ w2,
    const float* __restrict__ pL1, const float* __restrict__ pL2, const float* __restrict__ pS,
    const int* __restrict__ pI1, const int* __restrict__ pI2,
    float* __restrict__ rm, float* __restrict__ rs, int* __restrict__ ridx) {
  int t = threadIdx.x;
  int r = blockIdx.x * 4 + (t >> 6);
  int l = t & 63;
  float b1 = pL1[r], b2 = pL2[r], S = pS[r];
  int i1 = pI1[r], i2 = pI2[r];
  #pragma unroll
  for (int c = 1; c < NCS; ++c) {
    size_t o = (size_t)c * NROWS + r;
    float ob1 = pL1[o], ob2 = pL2[o], oS = pS[o];
    int oi1 = pI1[o], oi2 = pI2[o];
    float pb1 = b1;
    ins2(ob1, oi1, b1, i1, b2, i2);
    ins2(ob2, oi2, b1, i1, b2, i2);
    S = S * exp2f(pb1 - b1) + oS * exp2f(ob1 - b1);
  }
  int cand = (l < 32) ? i1 : i2;
  int lo = l & 31;
  const float* zr = zn + (size_t)r * 256;
  const float* wc = wn + (size_t)cand * 256;
  float d = 0.f;
  #pragma unroll
  for (int q = 0; q < 8; ++q) d += zr[lo + q*32] * wc[lo + q*32];
  #pragma unroll
  for (int mask = 1; mask <= 16; mask <<= 1) d += __shfl_xor(d, mask, 64);
  float dOther = __shfl_xor(d, 32, 64);
  if (l == 0) {
    float s1 = w2[i1] - 2.f*d;       // exact, z2 common term dropped
    float s2 = w2[i2] - 2.f*dOther;
    int win = i1;
    if (s2 < s1 || (s2 == s1 && i2 < i1)) win = i2;
    rm[r] = b1; rs[r] = S; ridx[r] = win;
  }
}

// ---- Pass 2 (MFMA): recompute logits; avg_probs + sample entropy ----
__global__ __attribute__((amdgpu_flat_work_group_size(1024,1024)))
__attribute__((amdgpu_waves_per_eu(4,4))) void k4_pass2(
    const u16* __restrict__ znh, const u16* __restrict__ znl,
    const u16* __restrict__ wnh, const u16* __restrict__ wnl,
    const float* __restrict__ rm, const float* __restrict__ rs,
    float* __restrict__ avgp, float* __restrict__ scal) {
  __shared__ u16 Cbuf[6][2][128*32];   // 96 KiB ring
  __shared__ float avgSlice[2048];     // 8 KiB: full cs slice accumulator
  __shared__ float red[1024];
  int t = threadIdx.x;
  int rb = blockIdx.x >> 2, cs = blockIdx.x & 3;
  int r0 = rb * 256;
  int w = t >> 6, l = t & 63;
  int g = l >> 4, lr = l & 15;
  int slotA = ((lr >> 1) & 3);

  for (int i = t; i < 2048; i += 1024) avgSlice[i] = 0.f;

  bf16x8 bh[8], bl[8];
  {
    size_t rbase = (size_t)(r0 + w*16 + lr) * 256;
    #pragma unroll
    for (int dc = 0; dc < 8; ++dc) {
      bh[dc] = *(const bf16x8*)&znh[rbase + dc*32 + g*8];
      bl[dc] = *(const bf16x8*)&znl[rbase + dc*32 + g*8];
    }
  }
  float m_, invS, l2s;
  {
    int r = r0 + w*16 + lr;
    float mm = rm[r], ss = rs[r];
    m_ = mm; invS = 1.f / ss; l2s = log2f(ss);
  }

  const size_t csbase = (size_t)cs * 2048 * 256;
  auto stage = [&](int s, int b) {
    if (w < 8) {
      int dc2 = s & 7;
      int krow = (s >> 3) * 128;
      int c = w*16 + (l >> 2);
      int qs = (l & 3) ^ ((l >> 3) & 3);
      size_t go = csbase + (size_t)(krow + c)*256 + dc2*32 + qs*8;
      gl_lds16(&wnh[go], &Cbuf[b][0][w*512]);
      gl_lds16(&wnl[go], &Cbuf[b][1][w*512]);
    }
  };
  DRAIN_VM();
  stage(0, 0);
  stage(1, 1);
  stage(2, 2);
  stage(3, 3);
  float ent = 0.f;

  for (int kt = 0; kt < 16; ++kt) {
    f32x4 acc[8];
    #pragma unroll
    for (int i = 0; i < 8; ++i) acc[i] = (f32x4){0.f,0.f,0.f,0.f};
    #pragma unroll
    for (int dcp = 0; dcp < 4; ++dcp) {
      int s0 = kt*8 + dcp*2;
      if (s0 < 126) PHASE_BARRIER_CNT(); else PHASE_BARRIER_ALL();
      if (s0 + 4 < 128) { int b4 = (s0+4) % 6; stage(s0 + 4, b4); }
      if (s0 + 5 < 128) { int b5 = (s0+5) % 6; stage(s0 + 5, b5); }
      #pragma unroll
      for (int h = 0; h < 2; ++h) {
        int dc = dcp*2 + h;
        int bR = (s0 + h) % 6;
        #pragma unroll
        for (int i = 0; i < 8; ++i) {
          int co = (i*16 + lr)*32 + (g ^ slotA)*8;
          bf16x8 ah = *(const bf16x8*)&Cbuf[bR][0][co];
          bf16x8 al = *(const bf16x8*)&Cbuf[bR][1][co];
          acc[i] = __builtin_amdgcn_mfma_f32_16x16x32_bf16(ah, bh[dc], acc[i], 0, 0, 0);
          acc[i] = __builtin_amdgcn_mfma_f32_16x16x32_bf16(ah, bl[dc], acc[i], 0, 0, 0);
          acc[i] = __builtin_amdgcn_mfma_f32_16x16x32_bf16(al, bh[dc], acc[i], 0, 0, 0);
        }
      }
    }
    int kb = cs*2048 + kt*128;
    // stats in two halves of 16 codeAcc (limits live registers)
    #pragma unroll
    for (int half = 0; half < 2; ++half) {
      float ca[16];
      #pragma unroll
      for (int n = 0; n < 16; ++n) ca[n] = 0.f;
      #pragma unroll
      for (int ii = 0; ii < 4; ++ii) {
        int i = half*4 + ii;
        #pragma unroll
        for (int v = 0; v < 4; ++v) {
          float tt = fmaf(CEXP, acc[i][v], -m_);
          float p = exp2f(tt) * invS;
          ent -= p * (tt - l2s);
          ca[ii*4+v] += p;
        }
      }
      #pragma unroll
      for (int n = 0; n < 16; ++n) {
        float sv = ca[n];
        sv += __shfl_xor(sv, 1, 64);
        sv += __shfl_xor(sv, 2, 64);
        sv += __shfl_xor(sv, 4, 64);
        sv += __shfl_xor(sv, 8, 64);
        if (lr == 0)
          atomicAdd(&avgSlice[kt*128 + (half*4 + (n>>2))*16 + g*4 + (n&3)], sv);
      }
    }
  }
  __syncthreads();
  for (int i = t; i < 2048; i += 1024)
    atomicAdd(&avgp[cs*2048 + i], avgSlice[i] * (1.f/16384.f));
  red[t] = ent;
  __syncthreads();
  for (int s2 = 512; s2; s2 >>= 1) { if (t < s2) red[t] += red[t + s2]; __syncthreads(); }
  if (t == 0) atomicAdd(&scal[1], red[0] * 0.6931471806f);   // exp2-space -> nat
}

// gather q = wn[idx], codebook loss, write z_q channel-first
__global__ __launch_bounds__(256) void k5_gather(const float* __restrict__ zn,
    const float* __restrict__ wn, const int* __restrict__ row_idx,
    float* __restrict__ out_zq, float* __restrict__ scal) {
  __shared__ float tile[256][33];
  __shared__ float red4[4];
  __shared__ float red[256];
  int bh = blockIdx.x, t = threadIdx.x;
  int b = bh >> 5, h = bh & 31;
  float cb = 0.f;
  for (int w = 0; w < 32; ++w) {
    int r = bh*32 + w;
    int idx = row_idx[r];
    float q = wn[(size_t)idx*256 + t];
    float s = q*q;
    #pragma unroll
    for (int mask = 32; mask; mask >>= 1) s += __shfl_xor(s, mask, 64);
    if ((t & 63) == 0) red4[t >> 6] = s;
    __syncthreads();
    float tot = red4[0] + red4[1] + red4[2] + red4[3];
    float inv = 1.f / fmaxf(sqrtf(tot), 1e-6f);
    float zv = zn[(size_t)r*256 + t];
    float d = q*inv - zv;
    cb += d*d;
    tile[t][w] = q;
    __syncthreads();
  }
  red[t] = cb;
  __syncthreads();
  for (int s2 = 128; s2; s2 >>= 1) { if (t < s2) red[t] += red[t+s2]; __syncthreads(); }
  if (t == 0) atomicAdd(&scal[0], red[0]);
  float* ob = out_zq + (size_t)b*256*1024 + (size_t)h*32;
  for (int j = 0; j < 32; ++j) {
    int i = t + j*256; int c = i >> 5, ww = i & 31;
    ob[(size_t)c*1024 + ww] = tile[c][ww];
  }
}

// finalize scalars + emit indices as float
__global__ __launch_bounds__(256) void k6_final(const float* __restrict__ avg_probs,
    const float* __restrict__ scal, const int* __restrict__ row_idx,
    float* __restrict__ out) {
  int t = threadIdx.x;
  if (blockIdx.x < 64) {
    int r = blockIdx.x*256 + t;
    out[4194307 + r] = (float)row_idx[r];
    return;
  }
  __shared__ float red[256];
  float s = 0.f;
  for (int j = 0; j < 32; ++j) {
    float v = avg_probs[t + j*256];
    s -= v * logf(v + 1e-5f);
  }
  red[t] = s;
  __syncthreads();
  for (int q = 128; q; q >>= 1) { if (t < q) red[t] += red[t+q]; __syncthreads(); }
  if (t == 0) {
    float avg_entropy = red[0];
    float sample_entropy = scal[1] * (1.f/16384.f);
    float cb = scal[0] * (1.f/4194304.f);
    out[4194304] = cb;
    out[4194305] = 0.25f * cb;
    out[4194306] = 0.1f * (sample_entropy - avg_entropy);
  }
}

extern "C" void kernel_launch(void* const* d_in, const int* in_sizes, int n_in,
                              void* d_out, int out_size, void* d_ws, size_t ws_size,
                              hipStream_t stream) {
  const float* z   = (const float*)d_in[0];
  const float* emb = (const float*)d_in[1];
  const float* pw  = (const float*)d_in[2];
  const float* pb  = (const float*)d_in[3];
  float* ws  = (float*)d_ws;
  float* out = (float*)d_out;
  float* wn   = ws + OFF_WN;
  float* w2   = ws + OFF_W2;
  float* zn   = ws + OFF_ZN;
  u16*   wnh  = (u16*)(ws + OFF_WNH);
  u16*   wnl  = (u16*)(ws + OFF_WNL);
  u16*   znh  = (u16*)(ws + OFF_ZNH);
  u16*   znl  = (u16*)(ws + OFF_ZNL);
  float* pL1  = ws + OFF_PL1;
  float* pL2  = ws + OFF_PL2;
  float* pS   = ws + OFF_PS;
  int*   pI1  = (int*)(ws + OFF_PI1);
  int*   pI2  = (int*)(ws + OFF_PI2);
  float* rm   = ws + OFF_RM;
  float* rs   = ws + OFF_RS;
  int*   ridx = (int*)(ws + OFF_RIDX);
  float* avgp = ws + OFF_AVGP;
  float* scal = ws + OFF_SCAL;

  k0_init<<<32, 256, 0, stream>>>(ws);
  k1_codebook<<<NCODES, 256, 0, stream>>>(emb, pw, pb, wn, w2, wnh, wnl);
  k2_zn<<<512, 256, 0, stream>>>(z, zn, znh, znl);
  k3_pass1<<<256, 1024, 0, stream>>>(znh, znl, wnh, wnl, pL1, pL2, pS, pI1, pI2);
  k3b_refine<<<NROWS/4, 256, 0, stream>>>(zn, wn, w2, pL1, pL2, pS, pI1, pI2, rm, rs, ridx);
  k4_pass2<<<256, 1024, 0, stream>>>(znh, znl, wnh, wnl, rm, rs, avgp, scal);
  k5_gather<<<512, 256, 0, stream>>>(zn, wn, ridx, out, scal);
  k6_final<<<65, 256, 0, stream>>>(avgp, scal, ridx, out);
}

// Round 23
// 781.718 us; speedup vs baseline: 1.1380x; 1.0247x over previous
//
#include <hip/hip_runtime.h>
#include <math.h>

// Problem constants
#define NROWS 16384      // B*H*W = 16*32*32
#define NCODES 8192
#define DIMS 256
#define NCS 4            // code-slices (2048 codes each); cs = blockIdx&3
#define CEXP 288.5390082f   // 200 * log2(e): logits in exp2-space, y = CEXP*dot

// ws layout (float offsets)
#define OFF_WN   0u          // fp32 wn       8192*256
#define OFF_W2   2097152u    // fp32 w2       8192
#define OFF_ZN   2105344u    // fp32 zn       16384*256
#define OFF_WNH  6299648u    // ushort wn_hi
#define OFF_WNL  7348224u    // ushort wn_lo
#define OFF_ZNH  8396800u    // ushort zn_hi
#define OFF_ZNL  10493952u   // ushort zn_lo
#define OFF_PL1  12591104u   // [4][16384] partial top1 logit (y-space)
#define OFF_PL2  12656640u   // [4][16384] partial top2 logit
#define OFF_PS   12722176u   // [4][16384] partial sum-exp2
#define OFF_PI1  12787712u   // [4][16384] partial top1 idx (int)
#define OFF_PI2  12853248u   // [4][16384] partial top2 idx (int)
#define OFF_RM   12918784u   // 16384 final row max (y-space)
#define OFF_RS   12935168u   // 16384 final row sum-exp2
#define OFF_RIDX 12951552u   // 16384 final exact argmin (int)
#define OFF_AVGP 12967936u   // 8192 avg_probs
#define OFF_SCAL 12976128u   // [0]=cb_sum [1]=ent_sum(nat)

typedef __attribute__((ext_vector_type(8))) short bf16x8;
typedef __attribute__((ext_vector_type(4))) float f32x4;
typedef unsigned short u16;

__device__ __forceinline__ u16 f2bf(float f) {
  unsigned u = __float_as_uint(f);
  u += 0x7fffu + ((u >> 16) & 1u);
  return (u16)(u >> 16);
}
__device__ __forceinline__ float bf2f(u16 s) { return __uint_as_float(((unsigned)s) << 16); }

__device__ __forceinline__ void gl_lds16(const u16* g, u16* l) {
  __builtin_amdgcn_global_load_lds(
      (const __attribute__((address_space(1))) unsigned*)g,
      (__attribute__((address_space(3))) unsigned*)l, 16, 0, 0);
}

// Phase = 2 chunks -> 4 stage-insts/wave/phase; vmcnt(4) leaves exactly the
// next phase's stages in flight (T4).
#define PHASE_BARRIER_CNT()  asm volatile("s_waitcnt vmcnt(4) lgkmcnt(0)\n\ts_barrier" ::: "memory")
#define PHASE_BARRIER_ALL()  asm volatile("s_waitcnt vmcnt(0) lgkmcnt(0)\n\ts_barrier" ::: "memory")
#define DRAIN_VM()           asm volatile("s_waitcnt vmcnt(0)" ::: "memory")

// top-2 insert ordered by (value desc, index asc)
__device__ __forceinline__ void ins2(float x, int idx, float& b1, int& i1, float& b2, int& i2) {
  if (x > b1 || (x == b1 && idx < i1)) { b2 = b1; i2 = i1; b1 = x; i1 = idx; }
  else if (x > b2 || (x == b2 && idx < i2)) { b2 = x; i2 = idx; }
}

__global__ __launch_bounds__(256) void k0_init(float* ws) {
  int i = blockIdx.x * 256 + threadIdx.x;
  if (i < NCODES) ws[OFF_AVGP + i] = 0.f;
  if (i < 16) ws[OFF_SCAL + i] = 0.f;
}

// weight = emb @ proj_w^T + b ; wn = normalize; w2 = sum(wn^2); + bf16 hi/lo planes
__global__ __launch_bounds__(256) void k1_codebook(const float* __restrict__ emb,
    const float* __restrict__ pw, const float* __restrict__ pb,
    float* __restrict__ wn, float* __restrict__ w2,
    u16* __restrict__ wnh, u16* __restrict__ wnl) {
  __shared__ float e[256];
  __shared__ float red[256];
  int k = blockIdx.x, t = threadIdx.x;
  e[t] = emb[(size_t)k * 256 + t];
  __syncthreads();
  const float4* prow = reinterpret_cast<const float4*>(pw + (size_t)t * 256);
  float acc = pb[t];
  #pragma unroll 8
  for (int q = 0; q < 64; ++q) {
    float4 p4 = prow[q];
    acc += e[q*4+0]*p4.x + e[q*4+1]*p4.y + e[q*4+2]*p4.z + e[q*4+3]*p4.w;
  }
  red[t] = acc * acc;
  __syncthreads();
  for (int s = 128; s; s >>= 1) { if (t < s) red[t] += red[t+s]; __syncthreads(); }
  float inv = 1.f / fmaxf(sqrtf(red[0]), 1e-6f);
  float v = acc * inv;
  size_t o = (size_t)k*256 + t;
  wn[o] = v;
  u16 hb = f2bf(v); float hf = bf2f(hb);
  wnh[o] = hb; wnl[o] = f2bf(v - hf);
  __syncthreads();
  red[t] = v * v;
  __syncthreads();
  for (int s = 128; s; s >>= 1) { if (t < s) red[t] += red[t+s]; __syncthreads(); }
  if (t == 0) w2[k] = red[0];
}

// zn = normalize over channel dim; zn row-major [row][C] + bf16 hi/lo
__global__ __launch_bounds__(256) void k2_zn(const float* __restrict__ z,
    float* __restrict__ zn, u16* __restrict__ znh, u16* __restrict__ znl) {
  __shared__ float tile[256][33];
  __shared__ float inv[32];
  int bh = blockIdx.x, t = threadIdx.x;
  const float* zb = z + (size_t)(bh >> 5) * (256*1024) + (size_t)(bh & 31) * 32;
  for (int j = 0; j < 32; ++j) {
    int i = t + j*256; int c = i >> 5, w = i & 31;
    tile[c][w] = zb[(size_t)c*1024 + w];
  }
  __syncthreads();
  if (t < 32) {
    float s = 0.f;
    for (int c = 0; c < 256; ++c) { float v = tile[c][t]; s += v*v; }
    inv[t] = 1.f / fmaxf(sqrtf(s), 1e-6f);
  }
  __syncthreads();
  size_t base = (size_t)bh * 32 * 256;
  for (int w = 0; w < 32; ++w) {
    float v = tile[t][w] * inv[w];
    size_t o = base + (size_t)w*256 + t;
    zn[o] = v;
    u16 hb = f2bf(v); float hf = bf2f(hb);
    znh[o] = hb; znl[o] = f2bf(v - hf);
  }
}

// ---- Pass 1 (MFMA): per-row online (max, sum-exp2, per-lane top-2). ----
// FINAL (R23): reverted to the measured-best R19 configuration (782.6us).
// Session verdict after 12 falsified single-lever hypotheses (occupancy x3
// incl. forced 4 waves/SIMD at 47% occupancy with NO perf change; barriers;
// staging traffic 4x down; bank conflicts -> 0 twice; register pin; de-spill;
// phase granularity 2x; setprio; XCD slicing; pipeline depth): the ~325us/
// pass plateau is the per-wave instruction-stream scheduling ceiling of this
// HIP-source structure (m97-class). The path beyond is an inline-asm K-loop /
// producer-consumer wave specialization rewrite.
__global__ __attribute__((amdgpu_flat_work_group_size(512,512)))
__attribute__((amdgpu_waves_per_eu(2,2))) void k3_pass1(
    const u16* __restrict__ znh, const u16* __restrict__ znl,
    const u16* __restrict__ wnh, const u16* __restrict__ wnl,
    float* __restrict__ pL1, float* __restrict__ pL2, float* __restrict__ pS,
    int* __restrict__ pI1, int* __restrict__ pI2) {
  __shared__ u16 Cbuf[6][2][128*32];    // 96 KiB ring of chunk-slots
  int t = threadIdx.x;
  int rb = blockIdx.x >> 2, cs = blockIdx.x & 3;
  int r0 = rb * 256;
  int w = t >> 6, l = t & 63;
  int g = l >> 4, lr = l & 15;
  int slotA = ((lr >> 1) & 3);          // read-side XOR component

  bf16x8 bh[2][8], bl[2][8];
  #pragma unroll
  for (int jr = 0; jr < 2; ++jr) {
    size_t rbase = (size_t)(r0 + w*32 + jr*16 + lr) * 256;
    #pragma unroll
    for (int dc = 0; dc < 8; ++dc) {
      bh[jr][dc] = *(const bf16x8*)&znh[rbase + dc*32 + g*8];
      bl[jr][dc] = *(const bf16x8*)&znl[rbase + dc*32 + g*8];
    }
  }
  #pragma unroll
  for (int jr = 0; jr < 2; ++jr)
    #pragma unroll
    for (int dc = 0; dc < 8; ++dc)
      asm volatile("" : "+v"(bh[jr][dc]), "+v"(bl[jr][dc]));

  const size_t csbase = (size_t)cs * 2048 * 256;
  auto stage = [&](int s, int b) {       // 2 VMEM insts per wave, coalesced
    int dc2 = s & 7;
    int krow = (s >> 3) * 128;
    int c = w*16 + (l >> 2);
    int qs = (l & 3) ^ ((l >> 3) & 3);   // inverse-swizzled source quad (same 64B line)
    size_t go = csbase + (size_t)(krow + c)*256 + dc2*32 + qs*8;
    gl_lds16(&wnh[go], &Cbuf[b][0][w*512]);
    gl_lds16(&wnl[go], &Cbuf[b][1][w*512]);
  };
  DRAIN_VM();
  stage(0, 0);
  stage(1, 1);
  stage(2, 2);
  stage(3, 3);

  float b1[2] = {-3.0e38f, -3.0e38f}, b2[2] = {-3.0e38f, -3.0e38f}, Sv[2] = {0.f, 0.f};
  int i1[2] = {0, 0}, i2[2] = {0, 0};   // encoded kt*32+n

  for (int kt = 0; kt < 16; ++kt) {
    f32x4 acc[8][2];
    #pragma unroll
    for (int i = 0; i < 8; ++i) { acc[i][0] = (f32x4){0.f,0.f,0.f,0.f}; acc[i][1] = (f32x4){0.f,0.f,0.f,0.f}; }
    #pragma unroll
    for (int dcp = 0; dcp < 4; ++dcp) {          // phase = 2 chunks (BK=64)
      int s0 = kt*8 + dcp*2;
      if (s0 < 126) PHASE_BARRIER_CNT(); else PHASE_BARRIER_ALL();
      if (s0 + 4 < 128) { int b4 = (s0+4) % 6; stage(s0 + 4, b4); }
      if (s0 + 5 < 128) { int b5 = (s0+5) % 6; stage(s0 + 5, b5); }
      #pragma unroll
      for (int h = 0; h < 2; ++h) {
        int dc = dcp*2 + h;
        int bR = (s0 + h) % 6;
        #pragma unroll
        for (int i = 0; i < 8; ++i) {
          int co = (i*16 + lr)*32 + (g ^ slotA)*8;    // swizzled read: conflict-free
          bf16x8 ah = *(const bf16x8*)&Cbuf[bR][0][co];
          bf16x8 al = *(const bf16x8*)&Cbuf[bR][1][co];
          acc[i][0] = __builtin_amdgcn_mfma_f32_16x16x32_bf16(ah, bh[0][dc], acc[i][0], 0, 0, 0);
          acc[i][1] = __builtin_amdgcn_mfma_f32_16x16x32_bf16(ah, bh[1][dc], acc[i][1], 0, 0, 0);
          acc[i][0] = __builtin_amdgcn_mfma_f32_16x16x32_bf16(ah, bl[0][dc], acc[i][0], 0, 0, 0);
          acc[i][1] = __builtin_amdgcn_mfma_f32_16x16x32_bf16(ah, bl[1][dc], acc[i][1], 0, 0, 0);
          acc[i][0] = __builtin_amdgcn_mfma_f32_16x16x32_bf16(al, bh[0][dc], acc[i][0], 0, 0, 0);
          acc[i][1] = __builtin_amdgcn_mfma_f32_16x16x32_bf16(al, bh[1][dc], acc[i][1], 0, 0, 0);
        }
      }
    }
    // per-kt stats: raw-acc top-2 chain + exp2-space sumexp (lane-local)
    int kb32 = kt * 32;
    #pragma unroll
    for (int jr = 0; jr < 2; ++jr) {
      float ob1 = b1[jr];
      #pragma unroll
      for (int n = 0; n < 32; ++n) {
        float x = acc[n>>2][jr][n&3];
        bool c1 = x > b1[jr];
        bool c2 = x > b2[jr];
        float hi = fmaxf(x, b1[jr]);
        float lo = fminf(x, b1[jr]);
        b2[jr] = fmaxf(lo, fminf(hi, b2[jr]));
        i2[jr] = c1 ? i1[jr] : (c2 ? (kb32 + n) : i2[jr]);
        b1[jr] = hi;
        i1[jr] = c1 ? (kb32 + n) : i1[jr];
      }
      float negCm = -CEXP * b1[jr];
      float ts0 = 0.f, ts1 = 0.f;
      #pragma unroll
      for (int n = 0; n < 32; n += 2) {
        ts0 += exp2f(fmaf(CEXP, acc[n>>2][jr][n&3],     negCm));
        ts1 += exp2f(fmaf(CEXP, acc[(n+1)>>2][jr][(n+1)&3], negCm));
      }
      Sv[jr] = Sv[jr] * exp2f(CEXP * (ob1 - b1[jr])) + (ts0 + ts1);
    }
  }
  // decode indices, convert to y-space, merge lanes over g (masks 16,32)
  float my[2], y2[2]; int gi1[2], gi2[2];
  #pragma unroll
  for (int jr = 0; jr < 2; ++jr) {
    int e1 = i1[jr], e2 = i2[jr];
    int base = cs*2048 + g*4;
    gi1[jr] = base + (e1>>5)*128 + ((e1>>2)&7)*16 + (e1&3);
    gi2[jr] = base + (e2>>5)*128 + ((e2>>2)&7)*16 + (e2&3);
    my[jr] = CEXP * b1[jr];
    y2[jr] = CEXP * b2[jr];
    #pragma unroll
    for (int mask = 16; mask <= 32; mask <<= 1) {
      float om  = __shfl_xor(my[jr], mask, 64);
      float oy2 = __shfl_xor(y2[jr], mask, 64);
      float oS  = __shfl_xor(Sv[jr], mask, 64);
      int   o1  = __shfl_xor(gi1[jr], mask, 64);
      int   o2  = __shfl_xor(gi2[jr], mask, 64);
      float pm = my[jr];
      ins2(om,  o1, my[jr], gi1[jr], y2[jr], gi2[jr]);
      ins2(oy2, o2, my[jr], gi1[jr], y2[jr], gi2[jr]);
      Sv[jr] = Sv[jr] * exp2f(pm - my[jr]) + oS * exp2f(om - my[jr]);
    }
  }
  if (g == 0) {
    #pragma unroll
    for (int jr = 0; jr < 2; ++jr) {
      int r = r0 + w*32 + jr*16 + lr;
      size_t o = (size_t)cs * NROWS + r;
      pL1[o] = my[jr]; pL2[o] = y2[jr]; pS[o] = Sv[jr];
      pI1[o] = gi1[jr]; pI2[o] = gi2[jr];
    }
  }
}

// merge 4 code-slice partials; exact fp32 re-score of top-2 -> final argmin
__global__ __launch_bounds__(256) void k3b_refine(
    const float* __restrict__ zn, const float* __restrict__ wn, const float* __restrict__ w2,
    const float* __restrict__ pL1, const float* __restrict__ pL2, const float* __restrict__ pS,
    const int* __restrict__ pI1, const int* __restrict__ pI2,
    float* __restrict__ rm, float* __restrict__ rs, int* __restrict__ ridx) {
  int t = threadIdx.x;
  int r = blockIdx.x * 4 + (t >> 6);
  int l = t & 63;
  float b1 = pL1[r], b2 = pL2[r], S = pS[r];
  int i1 = pI1[r], i2 = pI2[r];
  #pragma unroll
  for (int c = 1; c < NCS; ++c) {
    size_t o = (size_t)c * NROWS + r;
    float ob1 = pL1[o], ob2 = pL2[o], oS = pS[o];
    int oi1 = pI1[o], oi2 = pI2[o];
    float pb1 = b1;
    ins2(ob1, oi1, b1, i1, b2, i2);
    ins2(ob2, oi2, b1, i1, b2, i2);
    S = S * exp2f(pb1 - b1) + oS * exp2f(ob1 - b1);
  }
  int cand = (l < 32) ? i1 : i2;
  int lo = l & 31;
  const float* zr = zn + (size_t)r * 256;
  const float* wc = wn + (size_t)cand * 256;
  float d = 0.f;
  #pragma unroll
  for (int q = 0; q < 8; ++q) d += zr[lo + q*32] * wc[lo + q*32];
  #pragma unroll
  for (int mask = 1; mask <= 16; mask <<= 1) d += __shfl_xor(d, mask, 64);
  float dOther = __shfl_xor(d, 32, 64);
  if (l == 0) {
    float s1 = w2[i1] - 2.f*d;       // exact, z2 common term dropped
    float s2 = w2[i2] - 2.f*dOther;
    int win = i1;
    if (s2 < s1 || (s2 == s1 && i2 < i1)) win = i2;
    rm[r] = b1; rs[r] = S; ridx[r] = win;
  }
}

// ---- Pass 2 (MFMA): recompute logits; avg_probs + sample entropy ----
__global__ __attribute__((amdgpu_flat_work_group_size(512,512)))
__attribute__((amdgpu_waves_per_eu(2,2))) void k4_pass2(
    const u16* __restrict__ znh, const u16* __restrict__ znl,
    const u16* __restrict__ wnh, const u16* __restrict__ wnl,
    const float* __restrict__ rm, const float* __restrict__ rs,
    float* __restrict__ avgp, float* __restrict__ scal) {
  __shared__ u16 Cbuf[6][2][128*32];   // 96 KiB ring
  __shared__ float avgSlice[2048];     // 8 KiB: full cs slice accumulator
  __shared__ float red[512];
  int t = threadIdx.x;
  int rb = blockIdx.x >> 2, cs = blockIdx.x & 3;
  int r0 = rb * 256;
  int w = t >> 6, l = t & 63;
  int g = l >> 4, lr = l & 15;
  int slotA = ((lr >> 1) & 3);

  for (int i = t; i < 2048; i += 512) avgSlice[i] = 0.f;

  bf16x8 bh[2][8], bl[2][8];
  #pragma unroll
  for (int jr = 0; jr < 2; ++jr) {
    size_t rbase = (size_t)(r0 + w*32 + jr*16 + lr) * 256;
    #pragma unroll
    for (int dc = 0; dc < 8; ++dc) {
      bh[jr][dc] = *(const bf16x8*)&znh[rbase + dc*32 + g*8];
      bl[jr][dc] = *(const bf16x8*)&znl[rbase + dc*32 + g*8];
    }
  }
  #pragma unroll
  for (int jr = 0; jr < 2; ++jr)
    #pragma unroll
    for (int dc = 0; dc < 8; ++dc)
      asm volatile("" : "+v"(bh[jr][dc]), "+v"(bl[jr][dc]));

  float m_[2], invS[2], l2s[2];
  #pragma unroll
  for (int jr = 0; jr < 2; ++jr) {
    int r = r0 + w*32 + jr*16 + lr;
    float mm = rm[r], ss = rs[r];
    m_[jr] = mm; invS[jr] = 1.f / ss; l2s[jr] = log2f(ss);
  }

  const size_t csbase = (size_t)cs * 2048 * 256;
  auto stage = [&](int s, int b) {
    int dc2 = s & 7;
    int krow = (s >> 3) * 128;
    int c = w*16 + (l >> 2);
    int qs = (l & 3) ^ ((l >> 3) & 3);
    size_t go = csbase + (size_t)(krow + c)*256 + dc2*32 + qs*8;
    gl_lds16(&wnh[go], &Cbuf[b][0][w*512]);
    gl_lds16(&wnl[go], &Cbuf[b][1][w*512]);
  };
  DRAIN_VM();
  stage(0, 0);
  stage(1, 1);
  stage(2, 2);
  stage(3, 3);
  float ent = 0.f;

  for (int kt = 0; kt < 16; ++kt) {
    f32x4 acc[8][2];
    #pragma unroll
    for (int i = 0; i < 8; ++i) { acc[i][0] = (f32x4){0.f,0.f,0.f,0.f}; acc[i][1] = (f32x4){0.f,0.f,0.f,0.f}; }
    #pragma unroll
    for (int dcp = 0; dcp < 4; ++dcp) {
      int s0 = kt*8 + dcp*2;
      if (s0 < 126) PHASE_BARRIER_CNT(); else PHASE_BARRIER_ALL();
      if (s0 + 4 < 128) { int b4 = (s0+4) % 6; stage(s0 + 4, b4); }
      if (s0 + 5 < 128) { int b5 = (s0+5) % 6; stage(s0 + 5, b5); }
      #pragma unroll
      for (int h = 0; h < 2; ++h) {
        int dc = dcp*2 + h;
        int bR = (s0 + h) % 6;
        #pragma unroll
        for (int i = 0; i < 8; ++i) {
          int co = (i*16 + lr)*32 + (g ^ slotA)*8;
          bf16x8 ah = *(const bf16x8*)&Cbuf[bR][0][co];
          bf16x8 al = *(const bf16x8*)&Cbuf[bR][1][co];
          acc[i][0] = __builtin_amdgcn_mfma_f32_16x16x32_bf16(ah, bh[0][dc], acc[i][0], 0, 0, 0);
          acc[i][1] = __builtin_amdgcn_mfma_f32_16x16x32_bf16(ah, bh[1][dc], acc[i][1], 0, 0, 0);
          acc[i][0] = __builtin_amdgcn_mfma_f32_16x16x32_bf16(ah, bl[0][dc], acc[i][0], 0, 0, 0);
          acc[i][1] = __builtin_amdgcn_mfma_f32_16x16x32_bf16(ah, bl[1][dc], acc[i][1], 0, 0, 0);
          acc[i][0] = __builtin_amdgcn_mfma_f32_16x16x32_bf16(al, bh[0][dc], acc[i][0], 0, 0, 0);
          acc[i][1] = __builtin_amdgcn_mfma_f32_16x16x32_bf16(al, bh[1][dc], acc[i][1], 0, 0, 0);
        }
      }
    }
    // stats in two halves of 16 codesAcc (limits live registers)
    #pragma unroll
    for (int half = 0; half < 2; ++half) {
      float ca[16];
      #pragma unroll
      for (int n = 0; n < 16; ++n) ca[n] = 0.f;
      #pragma unroll
      for (int jr = 0; jr < 2; ++jr) {
        float is = invS[jr], l2 = l2s[jr];
        #pragma unroll
        for (int ii = 0; ii < 4; ++ii) {
          int i = half*4 + ii;
          #pragma unroll
          for (int v = 0; v < 4; ++v) {
            float tt = fmaf(CEXP, acc[i][jr][v], -m_[jr]);
            float p = exp2f(tt) * is;
            ent -= p * (tt - l2);
            ca[ii*4+v] += p;
          }
        }
      }
      #pragma unroll
      for (int n = 0; n < 16; ++n) {
        float sv = ca[n];
        sv += __shfl_xor(sv, 1, 64);
        sv += __shfl_xor(sv, 2, 64);
        sv += __shfl_xor(sv, 4, 64);
        sv += __shfl_xor(sv, 8, 64);
        if (lr == 0)
          atomicAdd(&avgSlice[kt*128 + (half*4 + (n>>2))*16 + g*4 + (n&3)], sv);
      }
    }
  }
  __syncthreads();
  for (int i = t; i < 2048; i += 512)
    atomicAdd(&avgp[cs*2048 + i], avgSlice[i] * (1.f/16384.f));
  red[t] = ent;
  __syncthreads();
  for (int s2 = 256; s2; s2 >>= 1) { if (t < s2) red[t] += red[t + s2]; __syncthreads(); }
  if (t == 0) atomicAdd(&scal[1], red[0] * 0.6931471806f);   // exp2-space -> nat
}

// gather q = wn[idx], codebook loss, write z_q channel-first
__global__ __launch_bounds__(256) void k5_gather(const float* __restrict__ zn,
    const float* __restrict__ wn, const int* __restrict__ row_idx,
    float* __restrict__ out_zq, float* __restrict__ scal) {
  __shared__ float tile[256][33];
  __shared__ float red4[4];
  __shared__ float red[256];
  int bh = blockIdx.x, t = threadIdx.x;
  int b = bh >> 5, h = bh & 31;
  float cb = 0.f;
  for (int w = 0; w < 32; ++w) {
    int r = bh*32 + w;
    int idx = row_idx[r];
    float q = wn[(size_t)idx*256 + t];
    float s = q*q;
    #pragma unroll
    for (int mask = 32; mask; mask >>= 1) s += __shfl_xor(s, mask, 64);
    if ((t & 63) == 0) red4[t >> 6] = s;
    __syncthreads();
    float tot = red4[0] + red4[1] + red4[2] + red4[3];
    float inv = 1.f / fmaxf(sqrtf(tot), 1e-6f);
    float zv = zn[(size_t)r*256 + t];
    float d = q*inv - zv;
    cb += d*d;
    tile[t][w] = q;
    __syncthreads();
  }
  red[t] = cb;
  __syncthreads();
  for (int s2 = 128; s2; s2 >>= 1) { if (t < s2) red[t] += red[t+s2]; __syncthreads(); }
  if (t == 0) atomicAdd(&scal[0], red[0]);
  float* ob = out_zq + (size_t)b*256*1024 + (size_t)h*32;
  for (int j = 0; j < 32; ++j) {
    int i = t + j*256; int c = i >> 5, ww = i & 31;
    ob[(size_t)c*1024 + ww] = tile[c][ww];
  }
}

// finalize scalars + emit indices as float
__global__ __launch_bounds__(256) void k6_final(const float* __restrict__ avg_probs,
    const float* __restrict__ scal, const int* __restrict__ row_idx,
    float* __restrict__ out) {
  int t = threadIdx.x;
  if (blockIdx.x < 64) {
    int r = blockIdx.x*256 + t;
    out[4194307 + r] = (float)row_idx[r];
    return;
  }
  __shared__ float red[256];
  float s = 0.f;
  for (int j = 0; j < 32; ++j) {
    float v = avg_probs[t + j*256];
    s -= v * logf(v + 1e-5f);
  }
  red[t] = s;
  __syncthreads();
  for (int q = 128; q; q >>= 1) { if (t < q) red[t] += red[t+q]; __syncthreads(); }
  if (t == 0) {
    float avg_entropy = red[0];
    float sample_entropy = scal[1] * (1.f/16384.f);
    float cb = scal[0] * (1.f/4194304.f);
    out[4194304] = cb;
    out[4194305] = 0.25f * cb;
    out[4194306] = 0.1f * (sample_entropy - avg_entropy);
  }
}

extern "C" void kernel_launch(void* const* d_in, const int* in_sizes, int n_in,
                              void* d_out, int out_size, void* d_ws, size_t ws_size,
                              hipStream_t stream) {
  const float* z   = (const float*)d_in[0];
  const float* emb = (const float*)d_in[1];
  const float* pw  = (const float*)d_in[2];
  const float* pb  = (const float*)d_in[3];
  float* ws  = (float*)d_ws;
  float* out = (float*)d_out;
  float* wn   = ws + OFF_WN;
  float* w2   = ws + OFF_W2;
  float* zn   = ws + OFF_ZN;
  u16*   wnh  = (u16*)(ws + OFF_WNH);
  u16*   wnl  = (u16*)(ws + OFF_WNL);
  u16*   znh  = (u16*)(ws + OFF_ZNH);
  u16*   znl  = (u16*)(ws + OFF_ZNL);
  float* pL1  = ws + OFF_PL1;
  float* pL2  = ws + OFF_PL2;
  float* pS   = ws + OFF_PS;
  int*   pI1  = (int*)(ws + OFF_PI1);
  int*   pI2  = (int*)(ws + OFF_PI2);
  float* rm   = ws + OFF_RM;
  float* rs   = ws + OFF_RS;
  int*   ridx = (int*)(ws + OFF_RIDX);
  float* avgp = ws + OFF_AVGP;
  float* scal = ws + OFF_SCAL;

  k0_init<<<32, 256, 0, stream>>>(ws);
  k1_codebook<<<NCODES, 256, 0, stream>>>(emb, pw, pb, wn, w2, wnh, wnl);
  k2_zn<<<512, 256, 0, stream>>>(z, zn, znh, znl);
  k3_pass1<<<256, 512, 0, stream>>>(znh, znl, wnh, wnl, pL1, pL2, pS, pI1, pI2);
  k3b_refine<<<NROWS/4, 256, 0, stream>>>(zn, wn, w2, pL1, pL2, pS, pI1, pI2, rm, rs, ridx);
  k4_pass2<<<256, 512, 0, stream>>>(znh, znl, wnh, wnl, rm, rs, avgp, scal);
  k5_gather<<<512, 256, 0, stream>>>(zn, wn, ridx, out, scal);
  k6_final<<<65, 256, 0, stream>>>(avgp, scal, ridx, out);
}